// Round 13
// baseline (363.435 us; speedup 1.0000x reference)
//
#include <hip/hip_runtime.h>
#include <stdint.h>

#define TGT 2048
#define BSZQ 4
#define EMB 1024
#define NHEAD 16
#define DH 64
#define BH 64      // BSZQ*NHEAD
#define MROWS 8192 // TGT*BSZQ

using short8 = __attribute__((ext_vector_type(8))) short;
using f32x4  = __attribute__((ext_vector_type(4))) float;
typedef unsigned short u16;
typedef unsigned int u32;

// 1/sqrt(64) * log2(e): scores exit QK^T in log2 domain; softmax = exp2(s)
#define QSCALE 0.18033688011112042f

__device__ __forceinline__ u16 f2bf(float f) { // RNE
  union { float f; u32 u; } v; v.f = f;
  return (u16)((v.u + 0x7fffu + ((v.u >> 16) & 1u)) >> 16);
}
__device__ __forceinline__ u32 packbf(float a, float b) {
  union { float f; u32 u; } x, y; x.f = a; y.f = b;
  return __builtin_amdgcn_perm(y.u + 0x8000u, x.u + 0x8000u, 0x07060302u);
}
__device__ __forceinline__ f32x4 mfma16(short8 a, short8 b, f32x4 c) {
  return __builtin_amdgcn_mfma_f32_16x16x32_bf16(a, b, c, 0, 0, 0);
}
__device__ __forceinline__ void gload_lds16(const u16* g, u16* l) {
  __builtin_amdgcn_global_load_lds((const __attribute__((address_space(1))) void*)g,
                                   (__attribute__((address_space(3))) void*)l,
                                   16, 0, 0);
}

// ---- f32 -> bf16 converts (memory-bound; round-6 validated pair) ----
__global__ __launch_bounds__(256)
void cvt3(const float* __restrict__ a, const float* __restrict__ b, const float* __restrict__ c,
          u16* __restrict__ oa, u16* __restrict__ ob, u16* __restrict__ oc)
{
  const float* s; u16* d;
  if (blockIdx.y == 0) { s = a; d = oa; }
  else if (blockIdx.y == 1) { s = b; d = ob; }
  else { s = c; d = oc; }
  const int i = (blockIdx.x * 256 + threadIdx.x) * 8;
  float4 v0 = *(const float4*)(s + i);
  float4 v1 = *(const float4*)(s + i + 4);
  union { u16 h[8]; short8 v; } r;
  r.h[0] = f2bf(v0.x); r.h[1] = f2bf(v0.y); r.h[2] = f2bf(v0.z); r.h[3] = f2bf(v0.w);
  r.h[4] = f2bf(v1.x); r.h[5] = f2bf(v1.y); r.h[6] = f2bf(v1.z); r.h[7] = f2bf(v1.w);
  *(short8*)(d + i) = r.v;
}
__global__ __launch_bounds__(256)
void cvt4(const float* __restrict__ a, const float* __restrict__ b,
          const float* __restrict__ c, const float* __restrict__ e,
          u16* __restrict__ oa, u16* __restrict__ ob, u16* __restrict__ oc, u16* __restrict__ oe)
{
  const float* s; u16* d;
  if (blockIdx.y == 0) { s = a; d = oa; }
  else if (blockIdx.y == 1) { s = b; d = ob; }
  else if (blockIdx.y == 2) { s = c; d = oc; }
  else { s = e; d = oe; }
  const int i = (blockIdx.x * 256 + threadIdx.x) * 8;
  float4 v0 = *(const float4*)(s + i);
  float4 v1 = *(const float4*)(s + i + 4);
  union { u16 h[8]; short8 v; } r;
  r.h[0] = f2bf(v0.x); r.h[1] = f2bf(v0.y); r.h[2] = f2bf(v0.z); r.h[3] = f2bf(v0.w);
  r.h[4] = f2bf(v1.x); r.h[5] = f2bf(v1.y); r.h[6] = f2bf(v1.z); r.h[7] = f2bf(v1.w);
  *(short8*)(d + i) = r.v;
}

// ---- GEMM: 128m x 128n tile, BK=64, SINGLE-buffered (round-6, 565 TF) ----
// 4 waves 2x2; each wave owns a 64x64 output sub-tile (acc[4][4]) ->
// 32 MFMA : 8 global_load_lds per wave per K-step. LDS 32 KB.
// Schedule experiments (BK=32 drain-0, no-LDS, counted-vmcnt, 256-tile)
// all regressed: this 2-barrier shape is the structure's local optimum.
// LDS rows 64-u16 wide, XOR-swizzled (slot group = g ^ (row&7)): staging is
// gload_lds-linear AND b128 frag reads are conflict-free.
// Grid is XCD-swizzled: the 8 n-tiles sharing an A-panel run on one XCD.
// SAFETY: all gemm_qkv outputs go to buffers NOT read by any concurrent
// block (qh->buf3, kh/vtp->d_out staging) so the swizzle cannot race.
// mode 0: *QSCALE, bf16 -> qh[(b*16+h)][t][d]
// mode 1:          bf16 -> kh[(b*16+h)][s][d]
// mode 2:          bf16 -> vtp[(b*16+h)][d][p64(t)],
//                  p64: c = (t&12)<<2 | (t&48)>>2 | (t&3)
//                  (flash PV b128-reads 8 consecutive u16)
// mode 3:          f32  -> out[m][n]
__device__ __forceinline__
void gemm_body(const u16* __restrict__ A, const u16* __restrict__ W,
               const float* __restrict__ bias, void* __restrict__ outp,
               u16* As, u16* Bs, int mode, int m0, int n0)
{
  const int tid = threadIdx.x;
  const int wave = tid >> 6, lane = tid & 63;
  const int col16 = lane & 15, quad = lane >> 4;
  const int wr = (wave >> 1) * 64;     // wave's row offset in the 128-tile
  const int wc = (wave & 1) * 64;      // wave's col offset in the 128-tile
  const int sr = lane >> 3;            // staging row-in-8
  const int sg = (lane & 7) ^ sr;      // staging source colgroup (XOR swizzle)
  const int fk = col16 & 7;            // frag-read swizzle key

#define GSTAGE(K0) do { \
  _Pragma("unroll") for (int s_ = 0; s_ < 4; ++s_) \
    gload_lds16(A + (size_t)(m0 + wave * 32 + s_ * 8 + sr) * EMB + (K0) + sg * 8, \
                &As[(wave * 32 + s_ * 8) * 64]); \
  _Pragma("unroll") for (int s_ = 0; s_ < 4; ++s_) \
    gload_lds16(W + (size_t)(n0 + wave * 32 + s_ * 8 + sr) * EMB + (K0) + sg * 8, \
                &Bs[(wave * 32 + s_ * 8) * 64]); \
} while (0)

  f32x4 acc[4][4];
#pragma unroll
  for (int i = 0; i < 4; ++i)
#pragma unroll
    for (int j = 0; j < 4; ++j) acc[i][j] = (f32x4)0.0f;

  for (int kt = 0; kt < EMB / 64; ++kt) {
    if (kt) __syncthreads();  // all frag reads of the buffer are done
    GSTAGE(kt * 64);
    __syncthreads();          // staged (vmcnt drained by barrier)
    short8 af[4][2], bfr[4][2];
#pragma unroll
    for (int kk = 0; kk < 2; ++kk) {
#pragma unroll
      for (int i = 0; i < 4; ++i)
        af[i][kk] = *(const short8*)&As[(wr + i * 16 + col16) * 64
                                        + (((kk * 4 + quad) ^ fk) << 3)];
#pragma unroll
      for (int j = 0; j < 4; ++j)
        bfr[j][kk] = *(const short8*)&Bs[(wc + j * 16 + col16) * 64
                                         + (((kk * 4 + quad) ^ fk) << 3)];
    }
#pragma unroll
    for (int i = 0; i < 4; ++i)
#pragma unroll
      for (int j = 0; j < 4; ++j) {
        acc[i][j] = mfma16(af[i][0], bfr[j][0], acc[i][j]);
        acc[i][j] = mfma16(af[i][1], bfr[j][1], acc[i][j]);
      }
  }
#undef GSTAGE

  const int rowb = quad * 4;
#pragma unroll
  for (int i = 0; i < 4; ++i) {
#pragma unroll
    for (int j = 0; j < 4; ++j) {
      const int gn = n0 + wc + j * 16 + col16;
      const float bia = bias[gn];
      const int h = gn >> 6, d = gn & 63;
#pragma unroll
      for (int r = 0; r < 4; ++r) {
        const int gm = m0 + wr + i * 16 + rowb + r;
        float val = acc[i][j][r] + bia;
        const int t = gm >> 2, b = gm & 3;
        if (mode == 0) {
          ((u16*)outp)[((size_t)(b * NHEAD + h) * TGT + t) * DH + d] = f2bf(val * QSCALE);
        } else if (mode == 1) {
          ((u16*)outp)[((size_t)(b * NHEAD + h) * TGT + t) * DH + d] = f2bf(val);
        } else if (mode == 2) {
          const int p = (t & ~63) + ((t & 12) << 2) + ((t & 48) >> 2) + (t & 3);
          ((u16*)outp)[((size_t)(b * NHEAD + h) * DH + d) * TGT + p] = f2bf(val);
        } else {
          ((float*)outp)[(size_t)gm * EMB + gn] = val;
        }
      }
    }
  }
}

// QKV fused: grid (8, 64, 3), XCD-swizzled work assignment (race-free:
// outputs never alias any concurrently-read buffer)
__global__ __launch_bounds__(256, 4)
void gemm_qkv(const u16* __restrict__ qb, const u16* __restrict__ kb, const u16* __restrict__ vb,
              const u16* __restrict__ wq, const u16* __restrict__ wk, const u16* __restrict__ wv,
              const float* __restrict__ bq, const float* __restrict__ bk, const float* __restrict__ bv,
              u16* __restrict__ qh, u16* __restrict__ kh, u16* __restrict__ vtp)
{
  __shared__ u16 As[8192];
  __shared__ u16 Bs[8192];
  // hardware block lin runs on XCD lin%8; give each XCD a contiguous run of
  // work ids so the 8 n-tiles sharing an A-panel execute on one XCD.
  const int lin = ((int)blockIdx.z * 64 + blockIdx.y) * 8 + blockIdx.x; // nwg=1536
  const int swz = (lin & 7) * 192 + (lin >> 3);
  const int n0 = (swz & 7) * 128;
  const int tmp = swz >> 3;
  const int m0 = (tmp & 63) * 128;
  const int z = tmp >> 6;
  const u16* A = (z == 0) ? qb : (z == 1) ? kb : vb;
  const u16* W = (z == 0) ? wq : (z == 1) ? wk : wv;
  const float* bias = (z == 0) ? bq : (z == 1) ? bk : bv;
  void* outp = (z == 0) ? (void*)qh : (z == 1) ? (void*)kh : (void*)vtp;
  gemm_body(A, W, bias, outp, As, Bs, z, m0, n0);
}

// Output projection: grid (8, 64), XCD-swizzled
__global__ __launch_bounds__(256, 4)
void gemm_o(const u16* __restrict__ A, const u16* __restrict__ W,
            const float* __restrict__ bias, float* __restrict__ outp)
{
  __shared__ u16 As[8192];
  __shared__ u16 Bs[8192];
  const int lin = (int)blockIdx.y * 8 + blockIdx.x; // nwg=512
  const int swz = (lin & 7) * 64 + (lin >> 3);
  const int n0 = (swz & 7) * 128;
  const int m0 = (swz >> 3) * 128;
  gemm_body(A, W, bias, (void*)outp, As, Bs, 3, m0, n0);
}

// ---- Flash attention: KVBLK=64, register-resident P (round-6 validated) ----
// Swapped QK^T: mfma(A=K-frag, B=Q-frag) puts P[kv=j*16+quad*4+r][q=col16]
// in registers. exp2+pack produce bf16 P fragments that feed PV directly as
// the A-operand of 16x16x32 MFMA (k-slot quad*8+e <-> kv (2h+(e>>2))*16+
// quad*4+(e&3)); the p64-permuted V^T rows make the matching V slice 8
// consecutive u16 (one b128 read). Zero P LDS traffic; Ps buffer gone.
// LDS = Ks 16K + Vs 16K = 32 KB. One barrier/tile, double-buffered async
// K/V staging, all XOR-swizzled.
__global__ __launch_bounds__(256, 4)
void flash_attn(const u16* __restrict__ qh, const u16* __restrict__ kh,
                const u16* __restrict__ vtp, u16* __restrict__ ao)
{
  __shared__ u16 Ks[2 * 64 * 64];   // [s][dh], slot g = src_g ^ (s&7)
  __shared__ u16 Vs[2 * 64 * 64];   // [d][p64(c)], slot g = src_g ^ (d&7)

  const int tid = threadIdx.x;
  const int wave = tid >> 6, lane = tid & 63;
  const int col16 = lane & 15, quad = lane >> 4;
  const int id = blockIdx.x;
  const int bh = (id & 7) * 8 + (id >> 7);   // 8 heads per XCD
  const int q0 = ((id >> 3) & 15) * 128;
  const int wq0 = q0 + wave * 32;

  const u16* qbase = qh + (size_t)bh * TGT * DH;
  const u16* kbase = kh + (size_t)bh * TGT * DH;
  const u16* vbase = vtp + (size_t)bh * DH * TGT;

  const int krl = lane >> 3;            // stage: row-in-8 (= swizzle key)
  const int kgl = (lane & 7) ^ krl;     // source colgroup (XOR swizzle)

#define STAGE(S0, B) do { \
  _Pragma("unroll") for (int t_ = 0; t_ < 2; ++t_) { \
    gload_lds16(kbase + (size_t)((S0) + t_ * 32 + wave * 8 + krl) * DH + kgl * 8, \
                &Ks[(B) * 4096 + (t_ * 32 + wave * 8) * 64]); \
    gload_lds16(vbase + (size_t)(t_ * 32 + wave * 8 + krl) * TGT + (S0) + kgl * 8, \
                &Vs[(B) * 4096 + (t_ * 32 + wave * 8) * 64]); \
  } } while (0)

  short8 qf[2][2];
#pragma unroll
  for (int i = 0; i < 2; ++i)
#pragma unroll
    for (int kk = 0; kk < 2; ++kk)
      qf[i][kk] = *(const short8*)(qbase + (size_t)(wq0 + i * 16 + col16) * DH + kk * 32 + quad * 8);

  f32x4 oacc[2][4];
  float lsum[2];
#pragma unroll
  for (int i = 0; i < 2; ++i) {
    lsum[i] = 0.0f;
#pragma unroll
    for (int j = 0; j < 4; ++j) oacc[i][j] = (f32x4)0.0f;
  }

  STAGE(0, 0);

  for (int st = 0; st < TGT / 64; ++st) {
    const int cb = st & 1;
    __syncthreads(); // buf[cb] staged (vmcnt drained by barrier); buf[cb^1] free
    if (st < TGT / 64 - 1) STAGE((st + 1) * 64, cb ^ 1);

    // Swapped QK^T: lane gets P[kv=j*16+quad*4+r][q=wq0+i*16+col16]
    u32 pka[4][2][2];
#pragma unroll
    for (int j = 0; j < 4; ++j) {
      const int R = j * 16 + col16;
      short8 kf0 = *(const short8*)&Ks[cb * 4096 + R * 64 + ((quad ^ (col16 & 7)) << 3)];
      short8 kf1 = *(const short8*)&Ks[cb * 4096 + R * 64 + (((quad + 4) ^ (col16 & 7)) << 3)];
#pragma unroll
      for (int i = 0; i < 2; ++i) {
        f32x4 t0 = mfma16(kf0, qf[i][0], (f32x4)0.0f);
        f32x4 s  = mfma16(kf1, qf[i][1], t0);
        float p0 = __builtin_amdgcn_exp2f(s[0]);
        float p1 = __builtin_amdgcn_exp2f(s[1]);
        float p2 = __builtin_amdgcn_exp2f(s[2]);
        float p3 = __builtin_amdgcn_exp2f(s[3]);
        lsum[i] += (p0 + p1) + (p2 + p3);
        pka[j][i][0] = packbf(p0, p1);
        pka[j][i][1] = packbf(p2, p3);
      }
    }
    // O += P V: 16x16x32 MFMA. A = concat of two packed P j-subtiles;
    // B = V^T b128 slice at p64 column quad*16 + h*8 (same kv order).
#pragma unroll
    for (int jd = 0; jd < 4; ++jd) {
      const int d = jd * 16 + col16;
#pragma unroll
      for (int h = 0; h < 2; ++h) {
        short8 vf = *(const short8*)&Vs[cb * 4096 + d * 64
                                        + (((quad * 2 + h) ^ (d & 7)) << 3)];
#pragma unroll
        for (int i = 0; i < 2; ++i) {
          union { u32 u[4]; short8 s8; } pa;
          pa.u[0] = pka[2 * h][i][0];     pa.u[1] = pka[2 * h][i][1];
          pa.u[2] = pka[2 * h + 1][i][0]; pa.u[3] = pka[2 * h + 1][i][1];
          oacc[i][jd] = mfma16(pa.s8, vf, oacc[i][jd]);
        }
      }
    }
  }
#undef STAGE

  // l: reduce over quads (kv split), invert, redistribute to q=quad*4+r rows
  float lrow[2][4];
#pragma unroll
  for (int i = 0; i < 2; ++i) {
    float L = lsum[i];
    L += __shfl_xor(L, 16, 64);
    L += __shfl_xor(L, 32, 64);
    L = __builtin_amdgcn_rcpf(L);
#pragma unroll
    for (int r = 0; r < 4; ++r) lrow[i][r] = __shfl(L, quad * 4 + r, 64);
  }
  const int b = bh >> 4, h = bh & 15;
#pragma unroll
  for (int i = 0; i < 2; ++i)
#pragma unroll
    for (int jd = 0; jd < 4; ++jd)
#pragma unroll
      for (int r = 0; r < 4; ++r) {
        const int t = q0 + wave * 32 + i * 16 + quad * 4 + r;
        const int d = jd * 16 + col16;
        ao[((size_t)t * BSZQ + b) * EMB + h * DH + d] = f2bf(oacc[i][jd][r] * lrow[i][r]);
      }
}

extern "C" void kernel_launch(void* const* d_in, const int* in_sizes, int n_in,
                              void* d_out, int out_size, void* d_ws, size_t ws_size,
                              hipStream_t stream) {
  const float* query = (const float*)d_in[0];
  const float* key   = (const float*)d_in[1];
  const float* value = (const float*)d_in[2];
  const float* Wq = (const float*)d_in[3];
  const float* bq = (const float*)d_in[4];
  const float* Wk = (const float*)d_in[5];
  const float* bk = (const float*)d_in[6];
  const float* Wv = (const float*)d_in[7];
  const float* bv = (const float*)d_in[8];
  const float* Wo = (const float*)d_in[9];
  const float* bo = (const float*)d_in[10];

  // workspace (u16 units). NO cross-launch aliasing hazards:
  //   gemm_qkv reads buf0/1/2+weights, writes buf3 + d_out staging (kh,vtp)
  //   flash    reads buf3 + d_out staging, writes buf2 (vbf dead)
  //   gemm_o   reads buf2 + wob, writes d_out (f32, staging dead)
  const size_t BIG = (size_t)MROWS * EMB; // 8388608
  const size_t WSZ = (size_t)EMB * EMB;   // 1048576
  u16* buf0 = (u16*)d_ws;        // qbf
  u16* buf1 = buf0 + BIG;        // kbf
  u16* buf2 = buf1 + BIG;        // vbf, then ao
  u16* buf3 = buf2 + BIG;        // qh
  u16* wqb  = buf3 + BIG;
  u16* wkb  = wqb + WSZ;
  u16* wvb  = wkb + WSZ;
  u16* wob  = wvb + WSZ;
  u16* khs  = (u16*)d_out;       // kh staging (d_out = 2*BIG u16, dead until gemm_o)
  u16* vts  = khs + BIG;         // vtp staging

  cvt3<<<dim3(BIG / 2048, 3), 256, 0, stream>>>(query, key, value, buf0, buf1, buf2);
  cvt4<<<dim3(WSZ / 2048, 4), 256, 0, stream>>>(Wq, Wk, Wv, Wo, wqb, wkb, wvb, wob);

  gemm_qkv<<<dim3(EMB / 128, MROWS / 128, 3), 256, 0, stream>>>(
      buf0, buf1, buf2, wqb, wkb, wvb, bq, bk, bv,
      buf3 /*qh*/, khs /*kh*/, vts /*vtp*/);

  flash_attn<<<1024, 256, 0, stream>>>(buf3, khs, vts, buf2); // ao -> buf2

  gemm_o<<<dim3(EMB / 128, MROWS / 128), 256, 0, stream>>>(buf2, wob, bo, (float*)d_out);
}

// Round 14
// 346.274 us; speedup vs baseline: 1.0496x; 1.0496x over previous
//
#include <hip/hip_runtime.h>
#include <stdint.h>

#define TGT 2048
#define BSZQ 4
#define EMB 1024
#define NHEAD 16
#define DH 64
#define BH 64      // BSZQ*NHEAD
#define MROWS 8192 // TGT*BSZQ

using short8 = __attribute__((ext_vector_type(8))) short;
using f32x4  = __attribute__((ext_vector_type(4))) float;
typedef unsigned short u16;
typedef unsigned int u32;

// 1/sqrt(64) * log2(e): scores exit QK^T in log2 domain; softmax = exp2(s)
#define QSCALE 0.18033688011112042f

__device__ __forceinline__ u16 f2bf(float f) { // RNE
  union { float f; u32 u; } v; v.f = f;
  return (u16)((v.u + 0x7fffu + ((v.u >> 16) & 1u)) >> 16);
}
__device__ __forceinline__ u32 packbf(float a, float b) {
  union { float f; u32 u; } x, y; x.f = a; y.f = b;
  return __builtin_amdgcn_perm(y.u + 0x8000u, x.u + 0x8000u, 0x07060302u);
}
__device__ __forceinline__ f32x4 mfma16(short8 a, short8 b, f32x4 c) {
  return __builtin_amdgcn_mfma_f32_16x16x32_bf16(a, b, c, 0, 0, 0);
}
__device__ __forceinline__ void gload_lds16(const u16* g, u16* l) {
  __builtin_amdgcn_global_load_lds((const __attribute__((address_space(1))) void*)g,
                                   (__attribute__((address_space(3))) void*)l,
                                   16, 0, 0);
}

// ---- f32 -> bf16 converts (memory-bound; round-6 validated pair) ----
__global__ __launch_bounds__(256)
void cvt3(const float* __restrict__ a, const float* __restrict__ b, const float* __restrict__ c,
          u16* __restrict__ oa, u16* __restrict__ ob, u16* __restrict__ oc)
{
  const float* s; u16* d;
  if (blockIdx.y == 0) { s = a; d = oa; }
  else if (blockIdx.y == 1) { s = b; d = ob; }
  else { s = c; d = oc; }
  const int i = (blockIdx.x * 256 + threadIdx.x) * 8;
  float4 v0 = *(const float4*)(s + i);
  float4 v1 = *(const float4*)(s + i + 4);
  union { u16 h[8]; short8 v; } r;
  r.h[0] = f2bf(v0.x); r.h[1] = f2bf(v0.y); r.h[2] = f2bf(v0.z); r.h[3] = f2bf(v0.w);
  r.h[4] = f2bf(v1.x); r.h[5] = f2bf(v1.y); r.h[6] = f2bf(v1.z); r.h[7] = f2bf(v1.w);
  *(short8*)(d + i) = r.v;
}
__global__ __launch_bounds__(256)
void cvt4(const float* __restrict__ a, const float* __restrict__ b,
          const float* __restrict__ c, const float* __restrict__ e,
          u16* __restrict__ oa, u16* __restrict__ ob, u16* __restrict__ oc, u16* __restrict__ oe)
{
  const float* s; u16* d;
  if (blockIdx.y == 0) { s = a; d = oa; }
  else if (blockIdx.y == 1) { s = b; d = ob; }
  else if (blockIdx.y == 2) { s = c; d = oc; }
  else { s = e; d = oe; }
  const int i = (blockIdx.x * 256 + threadIdx.x) * 8;
  float4 v0 = *(const float4*)(s + i);
  float4 v1 = *(const float4*)(s + i + 4);
  union { u16 h[8]; short8 v; } r;
  r.h[0] = f2bf(v0.x); r.h[1] = f2bf(v0.y); r.h[2] = f2bf(v0.z); r.h[3] = f2bf(v0.w);
  r.h[4] = f2bf(v1.x); r.h[5] = f2bf(v1.y); r.h[6] = f2bf(v1.z); r.h[7] = f2bf(v1.w);
  *(short8*)(d + i) = r.v;
}

// ---- GEMM: 128m x 128n tile, BK=64, SINGLE-buffered (round-6, 565 TF) ----
// 4 waves 2x2; each wave owns a 64x64 output sub-tile (acc[4][4]) ->
// 32 MFMA : 8 global_load_lds per wave per K-step. LDS 32 KB.
// Schedule experiments (BK=32 drain-0, no-LDS, counted-vmcnt, 256-tile)
// all regressed: this 2-barrier shape is the structure's local optimum.
// LDS rows 64-u16 wide, XOR-swizzled (slot group = g ^ (row&7)): staging is
// gload_lds-linear AND b128 frag reads are conflict-free.
// Grid is XCD-swizzled: the 8 n-tiles sharing an A-panel run on one XCD.
// SAFETY: all gemm_qkv outputs go to buffers NOT read by any concurrent
// block (qh->buf3, kh/vtp->d_out staging) so the swizzle cannot race.
// mode 0: *QSCALE, bf16 -> qh[(b*16+h)][t][d]
// mode 1:          bf16 -> kh[(b*16+h)][s][d]
// mode 2:          bf16 -> vtp[(b*16+h)][d][p64(t)],
//                  p64: c = (t&12)<<2 | (t&48)>>2 | (t&3)
//                  (flash PV b128-reads 8 consecutive u16)
// mode 3:          f32  -> out[m][n]
__device__ __forceinline__
void gemm_body(const u16* __restrict__ A, const u16* __restrict__ W,
               const float* __restrict__ bias, void* __restrict__ outp,
               u16* As, u16* Bs, int mode, int m0, int n0)
{
  const int tid = threadIdx.x;
  const int wave = tid >> 6, lane = tid & 63;
  const int col16 = lane & 15, quad = lane >> 4;
  const int wr = (wave >> 1) * 64;     // wave's row offset in the 128-tile
  const int wc = (wave & 1) * 64;      // wave's col offset in the 128-tile
  const int sr = lane >> 3;            // staging row-in-8
  const int sg = (lane & 7) ^ sr;      // staging source colgroup (XOR swizzle)
  const int fk = col16 & 7;            // frag-read swizzle key

#define GSTAGE(K0) do { \
  _Pragma("unroll") for (int s_ = 0; s_ < 4; ++s_) \
    gload_lds16(A + (size_t)(m0 + wave * 32 + s_ * 8 + sr) * EMB + (K0) + sg * 8, \
                &As[(wave * 32 + s_ * 8) * 64]); \
  _Pragma("unroll") for (int s_ = 0; s_ < 4; ++s_) \
    gload_lds16(W + (size_t)(n0 + wave * 32 + s_ * 8 + sr) * EMB + (K0) + sg * 8, \
                &Bs[(wave * 32 + s_ * 8) * 64]); \
} while (0)

  f32x4 acc[4][4];
#pragma unroll
  for (int i = 0; i < 4; ++i)
#pragma unroll
    for (int j = 0; j < 4; ++j) acc[i][j] = (f32x4)0.0f;

  for (int kt = 0; kt < EMB / 64; ++kt) {
    if (kt) __syncthreads();  // all frag reads of the buffer are done
    GSTAGE(kt * 64);
    __syncthreads();          // staged (vmcnt drained by barrier)
    short8 af[4][2], bfr[4][2];
#pragma unroll
    for (int kk = 0; kk < 2; ++kk) {
#pragma unroll
      for (int i = 0; i < 4; ++i)
        af[i][kk] = *(const short8*)&As[(wr + i * 16 + col16) * 64
                                        + (((kk * 4 + quad) ^ fk) << 3)];
#pragma unroll
      for (int j = 0; j < 4; ++j)
        bfr[j][kk] = *(const short8*)&Bs[(wc + j * 16 + col16) * 64
                                         + (((kk * 4 + quad) ^ fk) << 3)];
    }
#pragma unroll
    for (int i = 0; i < 4; ++i)
#pragma unroll
      for (int j = 0; j < 4; ++j) {
        acc[i][j] = mfma16(af[i][0], bfr[j][0], acc[i][j]);
        acc[i][j] = mfma16(af[i][1], bfr[j][1], acc[i][j]);
      }
  }
#undef GSTAGE

  const int rowb = quad * 4;
#pragma unroll
  for (int i = 0; i < 4; ++i) {
#pragma unroll
    for (int j = 0; j < 4; ++j) {
      const int gn = n0 + wc + j * 16 + col16;
      const float bia = bias[gn];
      const int h = gn >> 6, d = gn & 63;
#pragma unroll
      for (int r = 0; r < 4; ++r) {
        const int gm = m0 + wr + i * 16 + rowb + r;
        float val = acc[i][j][r] + bia;
        const int t = gm >> 2, b = gm & 3;
        if (mode == 0) {
          ((u16*)outp)[((size_t)(b * NHEAD + h) * TGT + t) * DH + d] = f2bf(val * QSCALE);
        } else if (mode == 1) {
          ((u16*)outp)[((size_t)(b * NHEAD + h) * TGT + t) * DH + d] = f2bf(val);
        } else if (mode == 2) {
          const int p = (t & ~63) + ((t & 12) << 2) + ((t & 48) >> 2) + (t & 3);
          ((u16*)outp)[((size_t)(b * NHEAD + h) * DH + d) * TGT + p] = f2bf(val);
        } else {
          ((float*)outp)[(size_t)gm * EMB + gn] = val;
        }
      }
    }
  }
}

// QKV fused: grid (8, 64, 3), XCD-swizzled work assignment (race-free:
// outputs never alias any concurrently-read buffer)
__global__ __launch_bounds__(256, 4)
void gemm_qkv(const u16* __restrict__ qb, const u16* __restrict__ kb, const u16* __restrict__ vb,
              const u16* __restrict__ wq, const u16* __restrict__ wk, const u16* __restrict__ wv,
              const float* __restrict__ bq, const float* __restrict__ bk, const float* __restrict__ bv,
              u16* __restrict__ qh, u16* __restrict__ kh, u16* __restrict__ vtp)
{
  __shared__ u16 As[8192];
  __shared__ u16 Bs[8192];
  // hardware block lin runs on XCD lin%8; give each XCD a contiguous run of
  // work ids so the 8 n-tiles sharing an A-panel execute on one XCD.
  const int lin = ((int)blockIdx.z * 64 + blockIdx.y) * 8 + blockIdx.x; // nwg=1536
  const int swz = (lin & 7) * 192 + (lin >> 3);
  const int n0 = (swz & 7) * 128;
  const int tmp = swz >> 3;
  const int m0 = (tmp & 63) * 128;
  const int z = tmp >> 6;
  const u16* A = (z == 0) ? qb : (z == 1) ? kb : vb;
  const u16* W = (z == 0) ? wq : (z == 1) ? wk : wv;
  const float* bias = (z == 0) ? bq : (z == 1) ? bk : bv;
  void* outp = (z == 0) ? (void*)qh : (z == 1) ? (void*)kh : (void*)vtp;
  gemm_body(A, W, bias, outp, As, Bs, z, m0, n0);
}

// Output projection: grid (8, 64), XCD-swizzled
__global__ __launch_bounds__(256, 4)
void gemm_o(const u16* __restrict__ A, const u16* __restrict__ W,
            const float* __restrict__ bias, float* __restrict__ outp)
{
  __shared__ u16 As[8192];
  __shared__ u16 Bs[8192];
  const int lin = (int)blockIdx.y * 8 + blockIdx.x; // nwg=512
  const int swz = (lin & 7) * 64 + (lin >> 3);
  const int n0 = (swz & 7) * 128;
  const int m0 = (swz >> 3) * 128;
  gemm_body(A, W, bias, (void*)outp, As, Bs, 3, m0, n0);
}

// ---- Flash attention: KVBLK=64, register-resident P (round-6 validated)
// + T5 s_setprio around the compute phase (attn-proven +4-7%, m191;
// mechanism: 4 blocks/CU at independent phases -> compute-phase waves win
// issue arbitration over staging-phase waves of co-resident blocks). ----
// Swapped QK^T: mfma(A=K-frag, B=Q-frag) puts P[kv=j*16+quad*4+r][q=col16]
// in registers. exp2+pack produce bf16 P fragments that feed PV directly as
// the A-operand of 16x16x32 MFMA (k-slot quad*8+e <-> kv (2h+(e>>2))*16+
// quad*4+(e&3)); the p64-permuted V^T rows make the matching V slice 8
// consecutive u16 (one b128 read). Zero P LDS traffic; Ps buffer gone.
// LDS = Ks 16K + Vs 16K = 32 KB. One barrier/tile, double-buffered async
// K/V staging, all XOR-swizzled.
__global__ __launch_bounds__(256, 4)
void flash_attn(const u16* __restrict__ qh, const u16* __restrict__ kh,
                const u16* __restrict__ vtp, u16* __restrict__ ao)
{
  __shared__ u16 Ks[2 * 64 * 64];   // [s][dh], slot g = src_g ^ (s&7)
  __shared__ u16 Vs[2 * 64 * 64];   // [d][p64(c)], slot g = src_g ^ (d&7)

  const int tid = threadIdx.x;
  const int wave = tid >> 6, lane = tid & 63;
  const int col16 = lane & 15, quad = lane >> 4;
  const int id = blockIdx.x;
  const int bh = (id & 7) * 8 + (id >> 7);   // 8 heads per XCD
  const int q0 = ((id >> 3) & 15) * 128;
  const int wq0 = q0 + wave * 32;

  const u16* qbase = qh + (size_t)bh * TGT * DH;
  const u16* kbase = kh + (size_t)bh * TGT * DH;
  const u16* vbase = vtp + (size_t)bh * DH * TGT;

  const int krl = lane >> 3;            // stage: row-in-8 (= swizzle key)
  const int kgl = (lane & 7) ^ krl;     // source colgroup (XOR swizzle)

#define STAGE(S0, B) do { \
  _Pragma("unroll") for (int t_ = 0; t_ < 2; ++t_) { \
    gload_lds16(kbase + (size_t)((S0) + t_ * 32 + wave * 8 + krl) * DH + kgl * 8, \
                &Ks[(B) * 4096 + (t_ * 32 + wave * 8) * 64]); \
    gload_lds16(vbase + (size_t)(t_ * 32 + wave * 8 + krl) * TGT + (S0) + kgl * 8, \
                &Vs[(B) * 4096 + (t_ * 32 + wave * 8) * 64]); \
  } } while (0)

  short8 qf[2][2];
#pragma unroll
  for (int i = 0; i < 2; ++i)
#pragma unroll
    for (int kk = 0; kk < 2; ++kk)
      qf[i][kk] = *(const short8*)(qbase + (size_t)(wq0 + i * 16 + col16) * DH + kk * 32 + quad * 8);

  f32x4 oacc[2][4];
  float lsum[2];
#pragma unroll
  for (int i = 0; i < 2; ++i) {
    lsum[i] = 0.0f;
#pragma unroll
    for (int j = 0; j < 4; ++j) oacc[i][j] = (f32x4)0.0f;
  }

  STAGE(0, 0);

  for (int st = 0; st < TGT / 64; ++st) {
    const int cb = st & 1;
    __syncthreads(); // buf[cb] staged (vmcnt drained by barrier); buf[cb^1] free
    if (st < TGT / 64 - 1) STAGE((st + 1) * 64, cb ^ 1);

    __builtin_amdgcn_s_setprio(1);  // compute phase: win CU issue arbitration

    // Swapped QK^T: lane gets P[kv=j*16+quad*4+r][q=wq0+i*16+col16]
    u32 pka[4][2][2];
#pragma unroll
    for (int j = 0; j < 4; ++j) {
      const int R = j * 16 + col16;
      short8 kf0 = *(const short8*)&Ks[cb * 4096 + R * 64 + ((quad ^ (col16 & 7)) << 3)];
      short8 kf1 = *(const short8*)&Ks[cb * 4096 + R * 64 + (((quad + 4) ^ (col16 & 7)) << 3)];
#pragma unroll
      for (int i = 0; i < 2; ++i) {
        f32x4 t0 = mfma16(kf0, qf[i][0], (f32x4)0.0f);
        f32x4 s  = mfma16(kf1, qf[i][1], t0);
        float p0 = __builtin_amdgcn_exp2f(s[0]);
        float p1 = __builtin_amdgcn_exp2f(s[1]);
        float p2 = __builtin_amdgcn_exp2f(s[2]);
        float p3 = __builtin_amdgcn_exp2f(s[3]);
        lsum[i] += (p0 + p1) + (p2 + p3);
        pka[j][i][0] = packbf(p0, p1);
        pka[j][i][1] = packbf(p2, p3);
      }
    }
    // O += P V: 16x16x32 MFMA. A = concat of two packed P j-subtiles;
    // B = V^T b128 slice at p64 column quad*16 + h*8 (same kv order).
#pragma unroll
    for (int jd = 0; jd < 4; ++jd) {
      const int d = jd * 16 + col16;
#pragma unroll
      for (int h = 0; h < 2; ++h) {
        short8 vf = *(const short8*)&Vs[cb * 4096 + d * 64
                                        + (((quad * 2 + h) ^ (d & 7)) << 3)];
#pragma unroll
        for (int i = 0; i < 2; ++i) {
          union { u32 u[4]; short8 s8; } pa;
          pa.u[0] = pka[2 * h][i][0];     pa.u[1] = pka[2 * h][i][1];
          pa.u[2] = pka[2 * h + 1][i][0]; pa.u[3] = pka[2 * h + 1][i][1];
          oacc[i][jd] = mfma16(pa.s8, vf, oacc[i][jd]);
        }
      }
    }

    __builtin_amdgcn_s_setprio(0);  // yield before barrier/stage of next tile
  }
#undef STAGE

  // l: reduce over quads (kv split), invert, redistribute to q=quad*4+r rows
  float lrow[2][4];
#pragma unroll
  for (int i = 0; i < 2; ++i) {
    float L = lsum[i];
    L += __shfl_xor(L, 16, 64);
    L += __shfl_xor(L, 32, 64);
    L = __builtin_amdgcn_rcpf(L);
#pragma unroll
    for (int r = 0; r < 4; ++r) lrow[i][r] = __shfl(L, quad * 4 + r, 64);
  }
  const int b = bh >> 4, h = bh & 15;
#pragma unroll
  for (int i = 0; i < 2; ++i)
#pragma unroll
    for (int jd = 0; jd < 4; ++jd)
#pragma unroll
      for (int r = 0; r < 4; ++r) {
        const int t = q0 + wave * 32 + i * 16 + quad * 4 + r;
        const int d = jd * 16 + col16;
        ao[((size_t)t * BSZQ + b) * EMB + h * DH + d] = f2bf(oacc[i][jd][r] * lrow[i][r]);
      }
}

extern "C" void kernel_launch(void* const* d_in, const int* in_sizes, int n_in,
                              void* d_out, int out_size, void* d_ws, size_t ws_size,
                              hipStream_t stream) {
  const float* query = (const float*)d_in[0];
  const float* key   = (const float*)d_in[1];
  const float* value = (const float*)d_in[2];
  const float* Wq = (const float*)d_in[3];
  const float* bq = (const float*)d_in[4];
  const float* Wk = (const float*)d_in[5];
  const float* bk = (const float*)d_in[6];
  const float* Wv = (const float*)d_in[7];
  const float* bv = (const float*)d_in[8];
  const float* Wo = (const float*)d_in[9];
  const float* bo = (const float*)d_in[10];

  // workspace (u16 units). NO cross-launch aliasing hazards:
  //   gemm_qkv reads buf0/1/2+weights, writes buf3 + d_out staging (kh,vtp)
  //   flash    reads buf3 + d_out staging, writes buf2 (vbf dead)
  //   gemm_o   reads buf2 + wob, writes d_out (f32, staging dead)
  const size_t BIG = (size_t)MROWS * EMB; // 8388608
  const size_t WSZ = (size_t)EMB * EMB;   // 1048576
  u16* buf0 = (u16*)d_ws;        // qbf
  u16* buf1 = buf0 + BIG;        // kbf
  u16* buf2 = buf1 + BIG;        // vbf, then ao
  u16* buf3 = buf2 + BIG;        // qh
  u16* wqb  = buf3 + BIG;
  u16* wkb  = wqb + WSZ;
  u16* wvb  = wkb + WSZ;
  u16* wob  = wvb + WSZ;
  u16* khs  = (u16*)d_out;       // kh staging (d_out = 2*BIG u16, dead until gemm_o)
  u16* vts  = khs + BIG;         // vtp staging

  cvt3<<<dim3(BIG / 2048, 3), 256, 0, stream>>>(query, key, value, buf0, buf1, buf2);
  cvt4<<<dim3(WSZ / 2048, 4), 256, 0, stream>>>(Wq, Wk, Wv, Wo, wqb, wkb, wvb, wob);

  gemm_qkv<<<dim3(EMB / 128, MROWS / 128, 3), 256, 0, stream>>>(
      buf0, buf1, buf2, wqb, wkb, wvb, bq, bk, bv,
      buf3 /*qh*/, khs /*kh*/, vts /*vtp*/);

  flash_attn<<<1024, 256, 0, stream>>>(buf3, khs, vts, buf2); // ao -> buf2

  gemm_o<<<dim3(EMB / 128, MROWS / 128), 256, 0, stream>>>(buf2, wob, bo, (float*)d_out);
}